// Round 1
// baseline (1377.394 us; speedup 1.0000x reference)
//
#include <hip/hip_runtime.h>
#include <math.h>

#define HH   128   // H
#define HH2  256   // 2H
#define HH3  384   // 3H
#define MB   16    // edges per block in the GRU kernel
#define TBK  512   // encoded-table bucket coverage

// ---------------- small prep kernels ----------------

__global__ void k_lastpos(const int* __restrict__ rel, const int* __restrict__ src,
                          int* __restrict__ lastpos, int N, int E) {
  int e = blockIdx.x * 256 + threadIdx.x;
  if (e >= E) return;
  atomicMax(&lastpos[rel[e] * N + src[e]], e);
}

__global__ void k_count(const int* __restrict__ rel, const int* __restrict__ src,
                        const int* __restrict__ lastpos, int* __restrict__ meta,
                        int N, int E) {
  int e = blockIdx.x * 256 + threadIdx.x;
  if (e >= E) return;
  int r = rel[e];
  if (lastpos[r * N + src[e]] == e) atomicAdd(&meta[r], 1);
}

// meta layout (ints): [0..15]=counts, [16..32]=offs, [33..49]=goff, [50]=total_groups, [51..66]=cursor
__global__ void k_scan(int* __restrict__ meta, int R) {
  if (threadIdx.x != 0 || blockIdx.x != 0) return;
  int off = 0, g = 0;
  meta[16] = 0; meta[33] = 0;
  for (int r = 0; r < R; r++) {
    int c = meta[r];
    off += c;
    g += (c + MB - 1) / MB;
    meta[16 + r + 1] = off;
    meta[33 + r + 1] = g;
    meta[51 + r] = meta[16 + r];  // cursor = offs[r]
  }
  meta[50] = g;
}

__global__ void k_scatter(const int* __restrict__ rel, const int* __restrict__ src,
                          const int* __restrict__ lastpos, int* __restrict__ meta,
                          int* __restrict__ bin, int N, int E) {
  int e = blockIdx.x * 256 + threadIdx.x;
  if (e >= E) return;
  int r = rel[e];
  if (lastpos[r * N + src[e]] == e) {
    int p = atomicAdd(&meta[51 + r], 1);
    bin[p] = e;
  }
}

// Wt[r][c][row] = W[r][row][c]   (rows = 3H, cols = 2H or H)
__global__ void k_transpose(const float* __restrict__ W, float* __restrict__ Wt,
                            int rows, int cols, int total) {
  int idx = blockIdx.x * 256 + threadIdx.x;
  if (idx >= total) return;
  int per = rows * cols;
  int r = idx / per;
  int rem = idx - r * per;
  int c = rem / rows;
  int row = rem - c * rows;
  Wt[idx] = W[(size_t)r * per + (size_t)row * cols + c];
}

// ET[r][b][h] = enc_W[r][h][b] + enc_b[r][h]   for b < TBK
__global__ void k_et(const float* __restrict__ encW, const float* __restrict__ encB,
                     float* __restrict__ ET, int R, int T) {
  int idx = blockIdx.x * 256 + threadIdx.x;
  int total = R * TBK * HH;
  if (idx >= total) return;
  int r = idx / (TBK * HH);
  int rem = idx - r * (TBK * HH);
  int b = rem / HH;
  int h = rem - b * HH;
  float v = 0.0f;
  if (b < T) v = encW[((size_t)r * HH + h) * (size_t)T + b] + encB[r * HH + h];
  ET[idx] = v;
}

__global__ void k_copy(const float4* __restrict__ in, float4* __restrict__ o, long long n4) {
  long long i = (long long)blockIdx.x * blockDim.x + threadIdx.x;
  long long stride = (long long)gridDim.x * blockDim.x;
  for (; i < n4; i += stride) o[i] = in[i];
}

// ---------------- main GRU kernel ----------------
// One block = MB winner edges of one relation. 128 threads: thread h owns output channel h.
// Accumulators: a_r/a_z share gi+gh contributions; a_in (input-side n), a_hn (hidden-side n) separate
// because ng = tanh(i_n + rg * h_n).
__global__ __launch_bounds__(128) void k_gru(
    const float* __restrict__ prev, const float* __restrict__ encW, const float* __restrict__ encB,
    const float* __restrict__ bih, const float* __restrict__ bhh,
    const int* __restrict__ src, const int* __restrict__ dst, const int* __restrict__ te,
    const int* __restrict__ ctp,
    const int* __restrict__ meta, const int* __restrict__ bin,
    const float* __restrict__ WtIh, const float* __restrict__ WtHh, const float* __restrict__ ET,
    float* __restrict__ out, int N, int T, int R) {
  int b = blockIdx.x;
  int total = meta[50];
  if (b >= total) return;
  // find relation: goff[r] <= b < goff[r+1]
  int r = 0;
  while (r + 1 < R && b >= meta[33 + r + 1]) r++;
  int g = b - meta[33 + r];
  int i0 = meta[16 + r] + g * MB;
  int mcnt = meta[16 + r + 1] - i0;
  if (mcnt > MB) mcnt = MB;

  __shared__ float xs[MB][HH2];
  __shared__ int sS[MB], sD[MB], sB[MB];
  int h = threadIdx.x;

  if (h < MB) {
    if (h < mcnt) {
      int e = bin[i0 + h];
      sS[h] = src[e];
      sD[h] = dst[e];
      int bk = *ctp - te[e];
      if (bk > T - 1) bk = T - 1;
      sB[h] = bk;
    } else {
      sS[h] = 0; sD[h] = 0; sB[h] = 0;
    }
  }
  __syncthreads();

  // build x = [encoded + u_j, u_i] into LDS (coalesced writes, bank-conflict-free)
  #pragma unroll
  for (int m = 0; m < MB; m++) {
    if (m < mcnt) {
      int s = sS[m], d = sD[m], bk = sB[m];
      float ui = prev[((size_t)r * N + s) * HH + h];
      float uj = prev[((size_t)r * N + d) * HH + h];
      float enc;
      if (bk < TBK) enc = ET[((size_t)r * TBK + bk) * HH + h];
      else          enc = encW[((size_t)r * HH + h) * (size_t)T + bk] + encB[r * HH + h];
      xs[m][h]      = enc + uj;
      xs[m][HH + h] = ui;
    } else {
      xs[m][h] = 0.0f; xs[m][HH + h] = 0.0f;
    }
  }
  __syncthreads();

  float a_r[MB], a_z[MB], a_in[MB], a_hn[MB];
  #pragma unroll
  for (int m = 0; m < MB; m++) { a_r[m] = 0.f; a_z[m] = 0.f; a_in[m] = 0.f; a_hn[m] = 0.f; }

  // gi: x[0..256) . W_ih rows  (transposed weights: coalesced over h)
  const float* Wi = WtIh + (size_t)r * HH2 * HH3;
  for (int j = 0; j < HH2; j += 4) {
    float wr[4], wz[4], wn[4];
    #pragma unroll
    for (int u = 0; u < 4; u++) {
      const float* row = Wi + (size_t)(j + u) * HH3;
      wr[u] = row[h]; wz[u] = row[HH + h]; wn[u] = row[2 * HH + h];
    }
    #pragma unroll
    for (int m = 0; m < MB; m++) {
      float4 xv = *(const float4*)&xs[m][j];  // LDS broadcast, conflict-free
      a_r[m]  += xv.x * wr[0] + xv.y * wr[1] + xv.z * wr[2] + xv.w * wr[3];
      a_z[m]  += xv.x * wz[0] + xv.y * wz[1] + xv.z * wz[2] + xv.w * wz[3];
      a_in[m] += xv.x * wn[0] + xv.y * wn[1] + xv.z * wn[2] + xv.w * wn[3];
    }
  }

  // gh: h_prev = x[128..256) . W_hh rows
  const float* Wh = WtHh + (size_t)r * HH * HH3;
  for (int j = 0; j < HH; j += 4) {
    float wr[4], wz[4], wn[4];
    #pragma unroll
    for (int u = 0; u < 4; u++) {
      const float* row = Wh + (size_t)(j + u) * HH3;
      wr[u] = row[h]; wz[u] = row[HH + h]; wn[u] = row[2 * HH + h];
    }
    #pragma unroll
    for (int m = 0; m < MB; m++) {
      float4 xv = *(const float4*)&xs[m][HH + j];
      a_r[m]  += xv.x * wr[0] + xv.y * wr[1] + xv.z * wr[2] + xv.w * wr[3];
      a_z[m]  += xv.x * wz[0] + xv.y * wz[1] + xv.z * wz[2] + xv.w * wz[3];
      a_hn[m] += xv.x * wn[0] + xv.y * wn[1] + xv.z * wn[2] + xv.w * wn[3];
    }
  }

  float bir = bih[r * HH3 + h], biz = bih[r * HH3 + HH + h], bin2 = bih[r * HH3 + 2 * HH + h];
  float bhr = bhh[r * HH3 + h], bhz = bhh[r * HH3 + HH + h], bhn  = bhh[r * HH3 + 2 * HH + h];

  for (int m = 0; m < mcnt; m++) {
    float rg = 1.f / (1.f + __expf(-(a_r[m] + bir + bhr)));
    float zg = 1.f / (1.f + __expf(-(a_z[m] + biz + bhz)));
    float ng = tanhf(a_in[m] + bin2 + rg * (a_hn[m] + bhn));
    float hp = xs[m][HH + h];
    out[((size_t)r * N + sS[m]) * HH + h] = (1.f - zg) * ng + zg * hp;
  }
}

// ---------------- launch ----------------

extern "C" void kernel_launch(void* const* d_in, const int* in_sizes, int n_in,
                              void* d_out, int out_size, void* d_ws, size_t ws_size,
                              hipStream_t stream) {
  const float* prev = (const float*)d_in[0];
  const float* encW = (const float*)d_in[1];
  const float* encB = (const float*)d_in[2];
  const float* Wih  = (const float*)d_in[3];
  const float* Whh  = (const float*)d_in[4];
  const float* bih  = (const float*)d_in[5];
  const float* bhh  = (const float*)d_in[6];
  const int* src = (const int*)d_in[7];
  const int* dst = (const int*)d_in[8];
  const int* rel = (const int*)d_in[9];
  const int* te  = (const int*)d_in[10];
  const int* ctp = (const int*)d_in[11];
  float* out = (float*)d_out;

  int E = in_sizes[7];
  int R = in_sizes[5] / HH3;            // b_ih is [R,3H]
  int N = in_sizes[0] / (R * HH);
  int T = in_sizes[1] / (2 * R * HH);

  // ws layout (4B elements): lastpos[R*N] | meta[128] | bin[E] | WtIh | WtHh | ET  (~10.3 MB)
  int* lastpos = (int*)d_ws;
  int* meta = lastpos + (size_t)R * N;
  int* bin = meta + 128;
  size_t off = (size_t)R * N + 128 + E;
  off = (off + 3) & ~(size_t)3;  // 16B align
  float* WtIh = (float*)d_ws + off;  off += (size_t)R * HH2 * HH3;
  float* WtHh = (float*)d_ws + off;  off += (size_t)R * HH * HH3;
  float* ET   = (float*)d_ws + off;  off += (size_t)R * TBK * HH;
  (void)ws_size;

  hipMemsetAsync(lastpos, 0xFF, (size_t)R * N * sizeof(int), stream);   // -1
  hipMemsetAsync(meta, 0, 128 * sizeof(int), stream);

  int eb = (E + 255) / 256;
  k_lastpos<<<eb, 256, 0, stream>>>(rel, src, lastpos, N, E);
  k_count<<<eb, 256, 0, stream>>>(rel, src, lastpos, meta, N, E);
  k_scan<<<1, 64, 0, stream>>>(meta, R);
  k_scatter<<<eb, 256, 0, stream>>>(rel, src, lastpos, meta, bin, N, E);

  int tIh = R * HH3 * HH2;
  int tHh = R * HH3 * HH;
  k_transpose<<<(tIh + 255) / 256, 256, 0, stream>>>(Wih, WtIh, HH3, HH2, tIh);
  k_transpose<<<(tHh + 255) / 256, 256, 0, stream>>>(Whh, WtHh, HH3, HH, tHh);
  int tET = R * TBK * HH;
  k_et<<<(tET + 255) / 256, 256, 0, stream>>>(encW, encB, ET, R, T);

  long long n4 = (long long)out_size / 4;
  k_copy<<<8192, 256, 0, stream>>>((const float4*)prev, (float4*)out, n4);

  int gruBlocks = (E + MB - 1) / MB + R;
  k_gru<<<gruBlocks, 128, 0, stream>>>(prev, encW, encB, bih, bhh, src, dst, te, ctp,
                                       meta, bin, WtIh, WtHh, ET, out, N, T, R);
}